// Round 18
// baseline (30.284 us; speedup 1.0000x reference)
//
#include <hip/hip_runtime.h>
#include <math.h>

#define RES 96
#define NV 97
#define NV2 (NV * NV)                      // 9409
#define NCELLS (RES * RES * RES)           // 884736
#define NBLK 3456                          // 24*24*6 tiles of 4x4x16
#define MAX_DISP (2.0f / 96.0f / 4.0f)
#define NVT 425                            // 5*5*17 tile vertices

typedef float f32x2u __attribute__((ext_vector_type(2), aligned(4)));

__device__ __forceinline__ float grid_coord(int a) {
    // linspace(-0.5,0.5,97)[a] * 2  ==  a/48 - 1
    return fmaf((float)a, 1.0f / 48.0f, -1.0f);
}

__device__ __forceinline__ float fast_tanh(float x) {
    x = fminf(fmaxf(x, -15.f), 15.f);
    const float e = __expf(2.f * x);
    return (e - 1.f) * __builtin_amdgcn_rcpf(e + 1.f);
}

// R13 structure + COALESCED weights staging. The direct per-thread 21-float
// row read was 21 loads x stride-84B = ~1760 cache-line touches per wave of
// TA work (every lane its own line, every load) — the term insensitive to
// occupancy/ILP that capped R13 at ~21us. Each wave's 4 cell-runs are
// contiguous 336-float spans: 24 coalesced loads (~96 line touches, 18x
// fewer) into a per-wave LDS region; lanes then read stride-21 from LDS
// (2-way bank aliasing = free on CDNA4). No extra barrier — the existing
// vs4 __syncthreads covers the wst writes too.
// Hard-won constraints: no nt hints (R12), no same-address atomic tails
// (R6/R7), no forced VGPR bounds (R11), no split passes (R16), no
// p-recompute (R14), 256-thread 4x4x16 tile (R10).
__global__ __launch_bounds__(256) void flexi_fused(
    const float* __restrict__ sdf,
    const float* __restrict__ deform,
    const float* __restrict__ weights,
    float* __restrict__ out_vd,
    float* __restrict__ partial)
{
    __shared__ float4 vs4[NVT];            // 6.8KB
    __shared__ float  wst[4][1344];        // 21.5KB: per-wave 4 runs x 336 floats
    __shared__ float  sm[8];

    const int t = threadIdx.x;
    const int lane = t & 63;
    const int w = t >> 6;                  // wave id == ti
    // chunked XCD swizzle: 8 XCDs x 432 contiguous tiles (bijective: 3456=8*432)
    const int bidx = (blockIdx.x & 7) * 432 + (blockIdx.x >> 3);
    const int bi = bidx / 144;             // i-tile (0..23)
    const int rb = bidx - bi * 144;
    const int bj = rb / 6;                 // j-tile (0..23)
    const int bk = rb - bj * 6;            // k-tile (0..5)

    // ---- coalesced weights staging: wave w stages runs (ti=w, tj=r) ----
    #pragma unroll
    for (int r = 0; r < 4; ++r) {
        const size_t fbase =
            (size_t)((4 * bi + w) * 9216 + (4 * bj + r) * 96 + 16 * bk) * 21;
        #pragma unroll
        for (int j = 0; j < 6; ++j) {
            const int u = j * 64 + lane;
            if (u < 336) wst[w][r * 336 + u] = weights[fbase + u];
        }
    }

    // ---- stage tile vertices: (deformed pos, sdf) as float4 ----
    #pragma unroll
    for (int it = 0; it < 2; ++it) {
        const int u = t + it * 256;
        if (u < NVT) {
            const int a  = u / 85;             // 0..4
            const int r  = u - a * 85;
            const int b  = r / 17;             // 0..4
            const int cc = r - b * 17;         // 0..16
            const int gv = (4 * bi + a) * NV2 + (4 * bj + b) * NV + 16 * bk + cc;
            const float* dp = deform + (size_t)gv * 3;
            const f32x2u d01 = *reinterpret_cast<const f32x2u*>(dp);
            const float  d2  = dp[2];
            float4 vv;
            vv.x = grid_coord(4 * bi + a)   + MAX_DISP * fast_tanh(d01.x);
            vv.y = grid_coord(4 * bj + b)   + MAX_DISP * fast_tanh(d01.y);
            vv.z = grid_coord(16 * bk + cc) + MAX_DISP * fast_tanh(d2);
            vv.w = sdf[gv];
            vs4[u] = vv;
        }
    }
    __syncthreads();                       // covers both wst and vs4

    // ---- per-cell weights from LDS (stride 21: 2-way aliasing, free) ----
    const int ti = t >> 6;
    const int tj = (t >> 4) & 3;
    const int tk = t & 15;
    float myw[21];                         // beta[0..11], alpha[12..19], gamma[20]
    #pragma unroll
    for (int e = 0; e < 21; ++e) myw[e] = wst[w][tj * 336 + tk * 21 + e];

    // ---- per-cell corners from LDS ----
    const int vbase = ti * 85 + tj * 17 + tk;
    const int OFF[8] = {0, 85, 17, 102, 1, 86, 18, 103};   // reference corner order

    float s[8], x[8][3];
    #pragma unroll
    for (int k = 0; k < 8; ++k) {
        const float4 vv = vs4[vbase + OFF[k]];
        x[k][0] = vv.x; x[k][1] = vv.y; x[k][2] = vv.z;
        s[k] = vv.w;
    }

    const int EA[12] = {0, 1, 4, 0, 2, 3, 6, 2, 2, 3, 7, 6};
    const int EB[12] = {1, 5, 5, 4, 3, 7, 7, 6, 0, 1, 5, 4};

    float p[12][3];
    bool  cross[12];
    float wsum = 0.f, vnum0 = 0.f, vnum1 = 0.f, vnum2 = 0.f;
    int   ncross = 0;
    #pragma unroll
    for (int e = 0; e < 12; ++e) {
        const int a = EA[e], b = EB[e];
        const float sa = s[a], sb = s[b];
        const bool cr = (sa > 0.f) != (sb > 0.f);
        cross[e] = cr;
        const float ta = myw[12 + a] * sb;
        const float tb = myw[12 + b] * sa;
        // den guard keeps p finite (w=0 masks its value, but 0*inf = NaN)
        const float den = cr ? (ta - tb) : 1.0f;
        const float inv = __builtin_amdgcn_rcpf(den);
        const float p0 = (ta * x[a][0] - tb * x[b][0]) * inv;
        const float p1 = (ta * x[a][1] - tb * x[b][1]) * inv;
        const float p2 = (ta * x[a][2] - tb * x[b][2]) * inv;
        p[e][0] = p0; p[e][1] = p1; p[e][2] = p2;
        const float w2 = cr ? myw[e] : 0.f;
        wsum  += w2;
        vnum0 += w2 * p0;
        vnum1 += w2 * p1;
        vnum2 += w2 * p2;
        ncross += cr ? 1 : 0;
    }

    const bool surf = (ncross > 0);
    const float invden = __builtin_amdgcn_rcpf(surf ? wsum : 1.0f);
    float vd0 = vnum0 * invden;
    float vd1 = vnum1 * invden;
    float vd2 = vnum2 * invden;
    if (!surf) { vd0 = 0.f; vd1 = 0.f; vd2 = 0.f; }

    const int c = (4 * bi + ti) * 9216 + (4 * bj + tj) * 96 + 16 * bk + tk;
    out_vd[(size_t)c * 3 + 0] = vd0;
    out_vd[(size_t)c * 3 + 1] = vd1;
    out_vd[(size_t)c * 3 + 2] = vd2;

    float devsum = 0.f;
    #pragma unroll
    for (int e = 0; e < 12; ++e) {
        const float d0 = p[e][0] - vd0;
        const float d1 = p[e][1] - vd1;
        const float d2 = p[e][2] - vd2;
        const float nrm = __builtin_amdgcn_sqrtf(d0 * d0 + d1 * d1 + d2 * d2 + 1e-12f);
        devsum += cross[e] ? nrm : 0.f;
    }
    const float dev = devsum * __builtin_amdgcn_rcpf(fmaxf((float)ncross, 1.0f));
    float regc = surf ? dev * myw[20] : 0.f;
    float cnt  = surf ? 1.0f : 0.f;

    #pragma unroll
    for (int off = 32; off > 0; off >>= 1) {
        regc += __shfl_down(regc, off);
        cnt  += __shfl_down(cnt, off);
    }
    const int wid = t >> 6;
    if ((t & 63) == 0) { sm[wid] = regc; sm[4 + wid] = cnt; }
    __syncthreads();
    if (t == 0) {
        partial[bidx]        = sm[0] + sm[1] + sm[2] + sm[3];
        partial[NBLK + bidx] = sm[4] + sm[5] + sm[6] + sm[7];
    }
}

__global__ __launch_bounds__(1024) void flexi_reduce(
    const float* __restrict__ partial, float* __restrict__ reg_out)
{
    float a = 0.f, b = 0.f;
    for (int i = threadIdx.x; i < NBLK; i += 1024) {
        a += partial[i];
        b += partial[NBLK + i];
    }
    #pragma unroll
    for (int off = 32; off > 0; off >>= 1) {
        a += __shfl_down(a, off);
        b += __shfl_down(b, off);
    }
    __shared__ float sm[32];
    const int wid = threadIdx.x >> 6;      // 16 waves
    if ((threadIdx.x & 63) == 0) { sm[wid] = a; sm[16 + wid] = b; }
    __syncthreads();
    if (threadIdx.x == 0) {
        float num = 0.f, den = 0.f;
        #pragma unroll
        for (int i = 0; i < 16; ++i) { num += sm[i]; den += sm[16 + i]; }
        reg_out[0] = num / fmaxf(den, 1.0f);
    }
}

extern "C" void kernel_launch(void* const* d_in, const int* in_sizes, int n_in,
                              void* d_out, int out_size, void* d_ws, size_t ws_size,
                              hipStream_t stream)
{
    // inputs: verts(analytic), indices(analytic), sdf, deform, weights
    const float* sdf     = (const float*)d_in[2];
    const float* deform  = (const float*)d_in[3];
    const float* weights = (const float*)d_in[4];
    float* out     = (float*)d_out;
    float* partial = (float*)d_ws;     // 2*NBLK floats, all rewritten each call

    flexi_fused<<<NBLK, 256, 0, stream>>>(sdf, deform, weights, out, partial);
    flexi_reduce<<<1, 1024, 0, stream>>>(partial, out + (size_t)NCELLS * 3);
}

// Round 19
// 27.643 us; speedup vs baseline: 1.0956x; 1.0956x over previous
//
#include <hip/hip_runtime.h>
#include <math.h>

#define RES 96
#define NV 97
#define NV2 (NV * NV)                      // 9409
#define NCELLS (RES * RES * RES)           // 884736
#define NBLK 3456                          // 24*24*6 tiles of 4x4x16
#define MAX_DISP (2.0f / 96.0f / 4.0f)
#define NVT 425                            // 5*5*17 tile vertices

typedef float f32x2u __attribute__((ext_vector_type(2), aligned(4)));

__device__ __forceinline__ float grid_coord(int a) {
    // linspace(-0.5,0.5,97)[a] * 2  ==  a/48 - 1
    return fmaf((float)a, 1.0f / 48.0f, -1.0f);
}

__device__ __forceinline__ float fast_tanh(float x) {
    x = fminf(fmaxf(x, -15.f), 15.f);
    const float e = __expf(2.f * x);
    return (e - 1.f) * __builtin_amdgcn_rcpf(e + 1.f);
}

// R13 + occupancy-NEUTRAL coalesced weights path. R13's 21 divergent
// stride-84B weight loads = ~1344 L1 tag-lookups/wave (TA-bound — the term
// insensitive to occupancy/ILP). R18 fixed TA but its 28.3KB LDS cut
// residency 8->5 blocks/CU and regressed. Here: 24 coalesced loads -> temp
// VGPRs (latency hidden under tanh staging), then each wave time-multiplexes
// ONE 336-float per-wave LDS buffer (4 rounds of ds_write + masked myw copy;
// per-wave region => same-wave LDS ordering, NO extra barrier). LDS = 12.2KB
// => 8 blocks/CU preserved. Banks: writes contiguous; reads tk*21%32 all
// distinct => conflict-free.
// Hard-won constraints: no nt hints (R12), no same-address atomic tails
// (R6/R7), no forced VGPR bounds (R11), no split passes (R16), no
// p-recompute (R14), 256-thread 4x4x16 tile (R10).
__global__ __launch_bounds__(256) void flexi_fused(
    const float* __restrict__ sdf,
    const float* __restrict__ deform,
    const float* __restrict__ weights,
    float* __restrict__ out_vd,
    float* __restrict__ partial)
{
    __shared__ float4 vs4[NVT];            // 6.8KB
    __shared__ float  wst[4][336];         // 5.4KB: per-wave staging buffer
    __shared__ float  sm[8];

    const int t = threadIdx.x;
    const int lane = t & 63;
    const int w = t >> 6;                  // wave id == ti
    // chunked XCD swizzle: 8 XCDs x 432 contiguous tiles (bijective: 3456=8*432)
    const int bidx = (blockIdx.x & 7) * 432 + (blockIdx.x >> 3);
    const int bi = bidx / 144;             // i-tile (0..23)
    const int rb = bidx - bi * 144;
    const int bj = rb / 6;                 // j-tile (0..23)
    const int bk = rb - bj * 6;            // k-tile (0..5)

    // ---- issue 24 coalesced weight loads into temps (in flight under tanh) ----
    // wave w covers runs (ti=w, tj=r): contiguous 336-float spans
    float wtmp[4][6];
    #pragma unroll
    for (int r = 0; r < 4; ++r) {
        const size_t fbase =
            (size_t)((4 * bi + w) * 9216 + (4 * bj + r) * 96 + 16 * bk) * 21;
        #pragma unroll
        for (int j = 0; j < 6; ++j) {
            const int u = j * 64 + lane;
            wtmp[r][j] = (u < 336) ? weights[fbase + u] : 0.f;
        }
    }

    // ---- stage tile vertices: (deformed pos, sdf) as float4 ----
    #pragma unroll
    for (int it = 0; it < 2; ++it) {
        const int u = t + it * 256;
        if (u < NVT) {
            const int a  = u / 85;             // 0..4
            const int r  = u - a * 85;
            const int b  = r / 17;             // 0..4
            const int cc = r - b * 17;         // 0..16
            const int gv = (4 * bi + a) * NV2 + (4 * bj + b) * NV + 16 * bk + cc;
            const float* dp = deform + (size_t)gv * 3;
            const f32x2u d01 = *reinterpret_cast<const f32x2u*>(dp);
            const float  d2  = dp[2];
            float4 vv;
            vv.x = grid_coord(4 * bi + a)   + MAX_DISP * fast_tanh(d01.x);
            vv.y = grid_coord(4 * bj + b)   + MAX_DISP * fast_tanh(d01.y);
            vv.z = grid_coord(16 * bk + cc) + MAX_DISP * fast_tanh(d2);
            vv.w = sdf[gv];
            vs4[u] = vv;
        }
    }
    __syncthreads();                       // vs4 ready

    // ---- per-wave weights distribution through the 336-float buffer ----
    // Same-wave LDS ops complete in order: no barrier needed for wst[w].
    const int ti = t >> 6;
    const int tj = (t >> 4) & 3;
    const int tk = t & 15;
    float myw[21];                         // beta[0..11], alpha[12..19], gamma[20]
    #pragma unroll
    for (int r = 0; r < 4; ++r) {
        #pragma unroll
        for (int j = 0; j < 6; ++j) {
            const int u = j * 64 + lane;
            if (u < 336) wst[w][u] = wtmp[r][j];
        }
        if (tj == r) {
            #pragma unroll
            for (int e = 0; e < 21; ++e) myw[e] = wst[w][tk * 21 + e];
        }
    }

    // ---- per-cell corners from LDS ----
    const int vbase = ti * 85 + tj * 17 + tk;
    const int OFF[8] = {0, 85, 17, 102, 1, 86, 18, 103};   // reference corner order

    float s[8], x[8][3];
    #pragma unroll
    for (int k = 0; k < 8; ++k) {
        const float4 vv = vs4[vbase + OFF[k]];
        x[k][0] = vv.x; x[k][1] = vv.y; x[k][2] = vv.z;
        s[k] = vv.w;
    }

    const int EA[12] = {0, 1, 4, 0, 2, 3, 6, 2, 2, 3, 7, 6};
    const int EB[12] = {1, 5, 5, 4, 3, 7, 7, 6, 0, 1, 5, 4};

    float p[12][3];
    bool  cross[12];
    float wsum = 0.f, vnum0 = 0.f, vnum1 = 0.f, vnum2 = 0.f;
    int   ncross = 0;
    #pragma unroll
    for (int e = 0; e < 12; ++e) {
        const int a = EA[e], b = EB[e];
        const float sa = s[a], sb = s[b];
        const bool cr = (sa > 0.f) != (sb > 0.f);
        cross[e] = cr;
        const float ta = myw[12 + a] * sb;
        const float tb = myw[12 + b] * sa;
        // den guard keeps p finite (w=0 masks its value, but 0*inf = NaN)
        const float den = cr ? (ta - tb) : 1.0f;
        const float inv = __builtin_amdgcn_rcpf(den);
        const float p0 = (ta * x[a][0] - tb * x[b][0]) * inv;
        const float p1 = (ta * x[a][1] - tb * x[b][1]) * inv;
        const float p2 = (ta * x[a][2] - tb * x[b][2]) * inv;
        p[e][0] = p0; p[e][1] = p1; p[e][2] = p2;
        const float w2 = cr ? myw[e] : 0.f;
        wsum  += w2;
        vnum0 += w2 * p0;
        vnum1 += w2 * p1;
        vnum2 += w2 * p2;
        ncross += cr ? 1 : 0;
    }

    const bool surf = (ncross > 0);
    const float invden = __builtin_amdgcn_rcpf(surf ? wsum : 1.0f);
    float vd0 = vnum0 * invden;
    float vd1 = vnum1 * invden;
    float vd2 = vnum2 * invden;
    if (!surf) { vd0 = 0.f; vd1 = 0.f; vd2 = 0.f; }

    const int c = (4 * bi + ti) * 9216 + (4 * bj + tj) * 96 + 16 * bk + tk;
    out_vd[(size_t)c * 3 + 0] = vd0;
    out_vd[(size_t)c * 3 + 1] = vd1;
    out_vd[(size_t)c * 3 + 2] = vd2;

    float devsum = 0.f;
    #pragma unroll
    for (int e = 0; e < 12; ++e) {
        const float d0 = p[e][0] - vd0;
        const float d1 = p[e][1] - vd1;
        const float d2 = p[e][2] - vd2;
        const float nrm = __builtin_amdgcn_sqrtf(d0 * d0 + d1 * d1 + d2 * d2 + 1e-12f);
        devsum += cross[e] ? nrm : 0.f;
    }
    const float dev = devsum * __builtin_amdgcn_rcpf(fmaxf((float)ncross, 1.0f));
    float regc = surf ? dev * myw[20] : 0.f;
    float cnt  = surf ? 1.0f : 0.f;

    #pragma unroll
    for (int off = 32; off > 0; off >>= 1) {
        regc += __shfl_down(regc, off);
        cnt  += __shfl_down(cnt, off);
    }
    const int wid = t >> 6;
    if ((t & 63) == 0) { sm[wid] = regc; sm[4 + wid] = cnt; }
    __syncthreads();
    if (t == 0) {
        partial[bidx]        = sm[0] + sm[1] + sm[2] + sm[3];
        partial[NBLK + bidx] = sm[4] + sm[5] + sm[6] + sm[7];
    }
}

__global__ __launch_bounds__(1024) void flexi_reduce(
    const float* __restrict__ partial, float* __restrict__ reg_out)
{
    float a = 0.f, b = 0.f;
    for (int i = threadIdx.x; i < NBLK; i += 1024) {
        a += partial[i];
        b += partial[NBLK + i];
    }
    #pragma unroll
    for (int off = 32; off > 0; off >>= 1) {
        a += __shfl_down(a, off);
        b += __shfl_down(b, off);
    }
    __shared__ float sm[32];
    const int wid = threadIdx.x >> 6;      // 16 waves
    if ((threadIdx.x & 63) == 0) { sm[wid] = a; sm[16 + wid] = b; }
    __syncthreads();
    if (threadIdx.x == 0) {
        float num = 0.f, den = 0.f;
        #pragma unroll
        for (int i = 0; i < 16; ++i) { num += sm[i]; den += sm[16 + i]; }
        reg_out[0] = num / fmaxf(den, 1.0f);
    }
}

extern "C" void kernel_launch(void* const* d_in, const int* in_sizes, int n_in,
                              void* d_out, int out_size, void* d_ws, size_t ws_size,
                              hipStream_t stream)
{
    // inputs: verts(analytic), indices(analytic), sdf, deform, weights
    const float* sdf     = (const float*)d_in[2];
    const float* deform  = (const float*)d_in[3];
    const float* weights = (const float*)d_in[4];
    float* out     = (float*)d_out;
    float* partial = (float*)d_ws;     // 2*NBLK floats, all rewritten each call

    flexi_fused<<<NBLK, 256, 0, stream>>>(sdf, deform, weights, out, partial);
    flexi_reduce<<<1, 1024, 0, stream>>>(partial, out + (size_t)NCELLS * 3);
}

// Round 20
// 25.676 us; speedup vs baseline: 1.1795x; 1.0766x over previous
//
#include <hip/hip_runtime.h>
#include <math.h>

#define RES 96
#define NV 97
#define NV2 (NV * NV)                      // 9409
#define NCELLS (RES * RES * RES)           // 884736
#define NBLK 3456                          // 24*24*6 tiles of 4x4x16
#define MAX_DISP (2.0f / 96.0f / 4.0f)
#define NVT 425                            // 5*5*17 tile vertices

typedef float f32x2u __attribute__((ext_vector_type(2), aligned(4)));

__device__ __forceinline__ float grid_coord(int a) {
    // linspace(-0.5,0.5,97)[a] * 2  ==  a/48 - 1
    return fmaf((float)a, 1.0f / 48.0f, -1.0f);
}

__device__ __forceinline__ float fast_tanh(float x) {
    x = fminf(fmaxf(x, -15.f), 15.f);
    const float e = __expf(2.f * x);
    return (e - 1.f) * __builtin_amdgcn_rcpf(e + 1.f);
}

// FINAL (exact R13 revert, 25.5us): fused single kernel, 4x4x16 tile,
// 256 threads. Vertices (pos+sdf float4) staged in 6.8KB LDS (wave-slot-
// capped 8 blocks/CU); weights read direct global->regs (21 dwords/thread);
// single-pass edge loop with p[] in registers; fast-math tanh/rcp/sqrt
// (error ~1e-6, 5 orders under threshold); XCD-chunked block swizzle;
// per-block partials to distinct addresses + tiny reduce kernel.
//
// Falsified levers (this session): weights-LDS tile (R12->R13: removing it
// won 5.9us); nt hints (R12: +3.7us L3 refetch); same-address atomic tails
// (R6/R7: +110us coherence-point serialization); forced VGPR bounds (R11:
// 145MB scratch spill); 128-thread tile (R10: +9us); split vdef pass (R16:
// +5.8us); p-recompute (R14: +2.7us); 2-cell ILP (R17: +0.7us); coalesced
// weights via LDS, both variants (R18/R19: +4.8/+2.1us); issue reorder
// (R15: neutral); launch_bounds(256,3) (R9: neutral).
__global__ __launch_bounds__(256) void flexi_fused(
    const float* __restrict__ sdf,
    const float* __restrict__ deform,
    const float* __restrict__ weights,
    float* __restrict__ out_vd,
    float* __restrict__ partial)
{
    __shared__ float4 vs4[NVT];            // (x,y,z,sdf) per tile vertex, 6.8KB
    __shared__ float  sm[8];

    const int t = threadIdx.x;
    // chunked XCD swizzle: 8 XCDs x 432 contiguous tiles (bijective: 3456=8*432)
    const int bidx = (blockIdx.x & 7) * 432 + (blockIdx.x >> 3);
    const int bi = bidx / 144;             // i-tile (0..23)
    const int rb = bidx - bi * 144;
    const int bj = rb / 6;                 // j-tile (0..23)
    const int bk = rb - bj * 6;            // k-tile (0..5)

    // ---- cell id + weights row loads issued FIRST (latency hides under tanh) ----
    const int ti = t >> 6;
    const int tj = (t >> 4) & 3;
    const int tk = t & 15;
    const int c = (4 * bi + ti) * 9216 + (4 * bj + tj) * 96 + 16 * bk + tk;
    const float* wrow = weights + (size_t)c * 21;
    float myw[21];                         // beta[0..11], alpha[12..19], gamma[20]
    #pragma unroll
    for (int e = 0; e < 21; ++e) myw[e] = wrow[e];

    // ---- stage tile vertices: (deformed pos, sdf) as float4 ----
    #pragma unroll
    for (int it = 0; it < 2; ++it) {
        const int u = t + it * 256;
        if (u < NVT) {
            const int a  = u / 85;             // 0..4
            const int r  = u - a * 85;
            const int b  = r / 17;             // 0..4
            const int cc = r - b * 17;         // 0..16
            const int gv = (4 * bi + a) * NV2 + (4 * bj + b) * NV + 16 * bk + cc;
            const float* dp = deform + (size_t)gv * 3;
            const f32x2u d01 = *reinterpret_cast<const f32x2u*>(dp);
            const float  d2  = dp[2];
            float4 vv;
            vv.x = grid_coord(4 * bi + a)   + MAX_DISP * fast_tanh(d01.x);
            vv.y = grid_coord(4 * bj + b)   + MAX_DISP * fast_tanh(d01.y);
            vv.z = grid_coord(16 * bk + cc) + MAX_DISP * fast_tanh(d2);
            vv.w = sdf[gv];
            vs4[u] = vv;
        }
    }
    __syncthreads();

    // ---- per-cell corners from LDS ----
    const int vbase = ti * 85 + tj * 17 + tk;
    const int OFF[8] = {0, 85, 17, 102, 1, 86, 18, 103};   // reference corner order

    float s[8], x[8][3];
    #pragma unroll
    for (int k = 0; k < 8; ++k) {
        const float4 vv = vs4[vbase + OFF[k]];
        x[k][0] = vv.x; x[k][1] = vv.y; x[k][2] = vv.z;
        s[k] = vv.w;
    }

    const int EA[12] = {0, 1, 4, 0, 2, 3, 6, 2, 2, 3, 7, 6};
    const int EB[12] = {1, 5, 5, 4, 3, 7, 7, 6, 0, 1, 5, 4};

    float p[12][3];
    bool  cross[12];
    float wsum = 0.f, vnum0 = 0.f, vnum1 = 0.f, vnum2 = 0.f;
    int   ncross = 0;
    #pragma unroll
    for (int e = 0; e < 12; ++e) {
        const int a = EA[e], b = EB[e];
        const float sa = s[a], sb = s[b];
        const bool cr = (sa > 0.f) != (sb > 0.f);
        cross[e] = cr;
        const float ta = myw[12 + a] * sb;
        const float tb = myw[12 + b] * sa;
        // den guard keeps p finite (w=0 masks its value, but 0*inf = NaN)
        const float den = cr ? (ta - tb) : 1.0f;
        const float inv = __builtin_amdgcn_rcpf(den);
        const float p0 = (ta * x[a][0] - tb * x[b][0]) * inv;
        const float p1 = (ta * x[a][1] - tb * x[b][1]) * inv;
        const float p2 = (ta * x[a][2] - tb * x[b][2]) * inv;
        p[e][0] = p0; p[e][1] = p1; p[e][2] = p2;
        const float w = cr ? myw[e] : 0.f;
        wsum  += w;
        vnum0 += w * p0;
        vnum1 += w * p1;
        vnum2 += w * p2;
        ncross += cr ? 1 : 0;
    }

    const bool surf = (ncross > 0);
    const float invden = __builtin_amdgcn_rcpf(surf ? wsum : 1.0f);
    float vd0 = vnum0 * invden;
    float vd1 = vnum1 * invden;
    float vd2 = vnum2 * invden;
    if (!surf) { vd0 = 0.f; vd1 = 0.f; vd2 = 0.f; }

    out_vd[(size_t)c * 3 + 0] = vd0;
    out_vd[(size_t)c * 3 + 1] = vd1;
    out_vd[(size_t)c * 3 + 2] = vd2;

    float devsum = 0.f;
    #pragma unroll
    for (int e = 0; e < 12; ++e) {
        const float d0 = p[e][0] - vd0;
        const float d1 = p[e][1] - vd1;
        const float d2 = p[e][2] - vd2;
        const float nrm = __builtin_amdgcn_sqrtf(d0 * d0 + d1 * d1 + d2 * d2 + 1e-12f);
        devsum += cross[e] ? nrm : 0.f;
    }
    const float dev = devsum * __builtin_amdgcn_rcpf(fmaxf((float)ncross, 1.0f));
    float regc = surf ? dev * myw[20] : 0.f;
    float cnt  = surf ? 1.0f : 0.f;

    #pragma unroll
    for (int off = 32; off > 0; off >>= 1) {
        regc += __shfl_down(regc, off);
        cnt  += __shfl_down(cnt, off);
    }
    const int wid = t >> 6;
    if ((t & 63) == 0) { sm[wid] = regc; sm[4 + wid] = cnt; }
    __syncthreads();
    if (t == 0) {
        partial[bidx]        = sm[0] + sm[1] + sm[2] + sm[3];
        partial[NBLK + bidx] = sm[4] + sm[5] + sm[6] + sm[7];
    }
}

__global__ __launch_bounds__(1024) void flexi_reduce(
    const float* __restrict__ partial, float* __restrict__ reg_out)
{
    float a = 0.f, b = 0.f;
    for (int i = threadIdx.x; i < NBLK; i += 1024) {
        a += partial[i];
        b += partial[NBLK + i];
    }
    #pragma unroll
    for (int off = 32; off > 0; off >>= 1) {
        a += __shfl_down(a, off);
        b += __shfl_down(b, off);
    }
    __shared__ float sm[32];
    const int wid = threadIdx.x >> 6;      // 16 waves
    if ((threadIdx.x & 63) == 0) { sm[wid] = a; sm[16 + wid] = b; }
    __syncthreads();
    if (threadIdx.x == 0) {
        float num = 0.f, den = 0.f;
        #pragma unroll
        for (int i = 0; i < 16; ++i) { num += sm[i]; den += sm[16 + i]; }
        reg_out[0] = num / fmaxf(den, 1.0f);
    }
}

extern "C" void kernel_launch(void* const* d_in, const int* in_sizes, int n_in,
                              void* d_out, int out_size, void* d_ws, size_t ws_size,
                              hipStream_t stream)
{
    // inputs: verts(analytic), indices(analytic), sdf, deform, weights
    const float* sdf     = (const float*)d_in[2];
    const float* deform  = (const float*)d_in[3];
    const float* weights = (const float*)d_in[4];
    float* out     = (float*)d_out;
    float* partial = (float*)d_ws;     // 2*NBLK floats, all rewritten each call

    flexi_fused<<<NBLK, 256, 0, stream>>>(sdf, deform, weights, out, partial);
    flexi_reduce<<<1, 1024, 0, stream>>>(partial, out + (size_t)NCELLS * 3);
}